// Round 9
// baseline (29.899 us; speedup 1.0000x reference)
//
#include <hip/hip_runtime.h>
#include <hip/hip_bf16.h>

#define NB 4
#define NH 16
#define SEQ 2048
#define EMB 512
#define DH 32
#define WIN 256

typedef __attribute__((ext_vector_type(8))) short short8;
typedef __attribute__((ext_vector_type(4))) float f32x4;

// packed f32x2 -> bf16x2 (RNE); HW-validated rounds 3/6/8
__device__ __forceinline__ unsigned cvt_pk_bf16(float lo, float hi) {
    unsigned r;
    asm("v_cvt_pk_bf16_f32 %0, %1, %2" : "=v"(r) : "v"(lo), "v"(hi));
    return r;
}

// === r8 (green, 26.4us) + ONE structural delta: 2 chunks per block ===
// Block = 4 waves / 256 thr handles chunks {2c,2c+1} (128 queries).
// Shared staging of the UNION key range [base, 128c+128), base =
// max(0,128c-256): 384 rows instead of 2x320 (-40% staging). Each wave
// interleaves two INDEPENDENT chunk streams in one t-loop -> 2x ILP on the
// latency-bound chain. All per-stream mechanics verbatim r8.
//
// Index math (verified c=0,1,2,15): kstartA = max(0,hiA-320) = base always
// -> A reads Ks/Vt at offset 0; offB = kstartB-base in {0,64}; staged rows
// base..base+383 <= 2047 (c=15 hits exactly 2047). KTA in {64..320},
// KTB in {128..320}, both multiples of 32; tiles guarded by 32t < KT.
//
// LDS: Ks [384][36] bf16 (27648 B; stride 18 words -> b128 reads hit all 16
// even bank-slots uniformly = min 8 sweeps, conflict-free) + Vt [32][392]
// (25088 B) + Pbuf 8 x [16][20] u32 (10240 B) = 62976 B -> 2 blocks/CU.

__global__ __launch_bounds__(256, 2)
void attn_chunk_kernel(const float* __restrict__ q, const float* __restrict__ k,
                       const float* __restrict__ v, float* __restrict__ out)
{
    constexpr int KSTR = 36;    // Ks row stride (bf16)
    constexpr int VSTR = 392;   // Vt row stride (bf16)
    constexpr int PSTR = 20;    // Pbuf row stride (u32)
    __shared__ __align__(16) ushort Ks[384 * KSTR];
    __shared__ __align__(16) ushort Vt[32 * VSTR];
    __shared__ __align__(16) unsigned Pbuf[8][16 * PSTR];

    // XCD-aware swizzle: 1024 blocks, 8 XCDs -> contiguous 128-block chunk/XCD
    const unsigned bid = (blockIdx.x & 7) * 128 + (blockIdx.x >> 3);
    const int cp = bid & 15;           // chunk-pair id
    const int h  = (bid >> 4) & 15;    // head
    const int b  = bid >> 8;           // batch
    const int q0A = cp * 128;          // chunk 2cp
    const int q0B = q0A + 64;          // chunk 2cp+1
    const int hiA = q0A + 64;
    const int hiB = q0B + 64;
    const int base = (q0A - 256 > 0) ? (q0A - 256) : 0;   // == kstartA
    const int KTA  = hiA - base;                          // 64..320
    const int kstartB = (hiB - 320 > 0) ? (hiB - 320) : 0;
    const int offB = kstartB - base;                      // 0 or 64
    const int KTB  = hiB - kstartB;                       // 128..320

    const int tid = threadIdx.x;
    const int e4  = (tid & 7) * 4;     // K-staging dim 0,4,..,28
    const int r0  = tid >> 3;          // K-staging key row 0..31
    const int d2  = (tid & 15) * 2;    // V-staging dim pair 0,2,..,30
    const int kp  = tid >> 4;          // V-staging key-pair 0..15

    // ---- staging loads: ALL issued first, unconditional (always in-bounds) ----
    float4 fk[12];
    float2 va[12], vb[12];
    #pragma unroll
    for (int it = 0; it < 12; ++it) {
        const size_t kbase = (size_t)(b * SEQ + base + r0 + it * 32) * EMB + h * DH + e4;
        fk[it] = *(const float4*)(k + kbase);
        const size_t vbase = (size_t)(b * SEQ + base + 32 * it + 2 * kp) * EMB + h * DH + d2;
        va[it] = *(const float2*)(v + vbase);          // key 32it+2kp, dims d2,d2+1
        vb[it] = *(const float2*)(v + vbase + EMB);    // key 32it+2kp+1
    }

    const int w   = tid >> 6;          // wave 0..3: queries [16w,16w+16) of each chunk
    const int l   = tid & 63;
    const int l16 = l & 15;
    const int kg  = l >> 4;            // 0..3
    const int k0  = kg * 8;            // dim slice for frags

    // ---- Q B-frags (both chunks) direct from global ----
    const float* qrowA = q + ((size_t)(b * SEQ + q0A + 16 * w + l16) * EMB + h * DH + k0);
    const float* qrowB = q + ((size_t)(b * SEQ + q0B + 16 * w + l16) * EMB + h * DH + k0);
    const float4 qa1 = *(const float4*)qrowA;
    const float4 qa2 = *(const float4*)(qrowA + 4);
    const float4 qb1 = *(const float4*)qrowB;
    const float4 qb2 = *(const float4*)(qrowB + 4);
    union { short8 s; unsigned u[4]; } qfA, qfB;
    qfA.u[0] = cvt_pk_bf16(qa1.x, qa1.y);
    qfA.u[1] = cvt_pk_bf16(qa1.z, qa1.w);
    qfA.u[2] = cvt_pk_bf16(qa2.x, qa2.y);
    qfA.u[3] = cvt_pk_bf16(qa2.z, qa2.w);
    qfB.u[0] = cvt_pk_bf16(qb1.x, qb1.y);
    qfB.u[1] = cvt_pk_bf16(qb1.z, qb1.w);
    qfB.u[2] = cvt_pk_bf16(qb2.x, qb2.y);
    qfB.u[3] = cvt_pk_bf16(qb2.z, qb2.w);

    // ---- staging converts + LDS writes (unconditional) ----
    #pragma unroll
    for (int it = 0; it < 12; ++it) {
        uint2 kw;
        kw.x = cvt_pk_bf16(fk[it].x, fk[it].y);
        kw.y = cvt_pk_bf16(fk[it].z, fk[it].w);
        *(uint2*)(Ks + (r0 + it * 32) * KSTR + e4) = kw;   // 8B aligned
        *(unsigned*)(Vt + (d2 + 0) * VSTR + 32 * it + 2 * kp) = cvt_pk_bf16(va[it].x, vb[it].x);
        *(unsigned*)(Vt + (d2 + 1) * VSTR + 32 * it + 2 * kp) = cvt_pk_bf16(va[it].y, vb[it].y);
    }
    __syncthreads();   // the only barrier

    const float scale = 0.17677669529663687f;  // 1/sqrt(32)
    const int iqA   = q0A + 16 * w + l16;
    const int iqB   = q0B + 16 * w + l16;
    const int lowkA = iqA - (WIN - 1);         // allowed A-keys: [lowkA, hiA)
    const int lowkB = iqB - (WIN - 1);         // allowed B-keys: [lowkB, hiB)
    unsigned* pwA = &Pbuf[2 * w + 0][l16 * PSTR];
    unsigned* pwB = &Pbuf[2 * w + 1][l16 * PSTR];

    const f32x4 zero = {0.f, 0.f, 0.f, 0.f};
    f32x4 o0A = zero, o1A = zero, o0B = zero, o1B = zero;
    float srowA = 0.f, srowB = 0.f;

    #pragma unroll
    for (int t = 0; t < 10; ++t) {
        // ---------- chunk A stream (buffer offset 0) ----------
        if (t * 32 < KTA) {
            const short8 ka = *(const short8*)(Ks + (32 * t + l16) * KSTR + k0);
            const short8 kb = *(const short8*)(Ks + (32 * t + 16 + l16) * KSTR + k0);
            f32x4 s_lo = __builtin_amdgcn_mfma_f32_16x16x32_bf16(ka, qfA.s, zero, 0, 0, 0);
            f32x4 s_hi = __builtin_amdgcn_mfma_f32_16x16x32_bf16(kb, qfA.s, zero, 0, 0, 0);
            const int kk = base + 32 * t + 4 * kg;
            float p[8];
            #pragma unroll
            for (int r = 0; r < 4; ++r) {
                p[r]     = (kk + r      >= lowkA) ? __expf(s_lo[r] * scale) : 0.f;
                p[r + 4] = (kk + r + 16 >= lowkA) ? __expf(s_hi[r] * scale) : 0.f;
            }
            srowA += ((p[0] + p[1]) + (p[2] + p[3])) + ((p[4] + p[5]) + (p[6] + p[7]));
            uint2 wlo, whi;
            wlo.x = cvt_pk_bf16(p[0], p[1]);  wlo.y = cvt_pk_bf16(p[2], p[3]);
            whi.x = cvt_pk_bf16(p[4], p[5]);  whi.y = cvt_pk_bf16(p[6], p[7]);
            *(uint2*)(pwA + 2 * kg)     = wlo;
            *(uint2*)(pwA + 8 + 2 * kg) = whi;
            const short8 pa = *(const short8*)(pwA + 4 * kg);
            const short8 bv0 = *(const short8*)(Vt + l16 * VSTR + 32 * t + k0);
            const short8 bv1 = *(const short8*)(Vt + (16 + l16) * VSTR + 32 * t + k0);
            o0A = __builtin_amdgcn_mfma_f32_16x16x32_bf16(pa, bv0, o0A, 0, 0, 0);
            o1A = __builtin_amdgcn_mfma_f32_16x16x32_bf16(pa, bv1, o1A, 0, 0, 0);
        }
        // ---------- chunk B stream (buffer offset offB) ----------
        if (t * 32 < KTB) {
            const short8 ka = *(const short8*)(Ks + (offB + 32 * t + l16) * KSTR + k0);
            const short8 kb = *(const short8*)(Ks + (offB + 32 * t + 16 + l16) * KSTR + k0);
            f32x4 s_lo = __builtin_amdgcn_mfma_f32_16x16x32_bf16(ka, qfB.s, zero, 0, 0, 0);
            f32x4 s_hi = __builtin_amdgcn_mfma_f32_16x16x32_bf16(kb, qfB.s, zero, 0, 0, 0);
            const int kk = kstartB + 32 * t + 4 * kg;
            float p[8];
            #pragma unroll
            for (int r = 0; r < 4; ++r) {
                p[r]     = (kk + r      >= lowkB) ? __expf(s_lo[r] * scale) : 0.f;
                p[r + 4] = (kk + r + 16 >= lowkB) ? __expf(s_hi[r] * scale) : 0.f;
            }
            srowB += ((p[0] + p[1]) + (p[2] + p[3])) + ((p[4] + p[5]) + (p[6] + p[7]));
            uint2 wlo, whi;
            wlo.x = cvt_pk_bf16(p[0], p[1]);  wlo.y = cvt_pk_bf16(p[2], p[3]);
            whi.x = cvt_pk_bf16(p[4], p[5]);  whi.y = cvt_pk_bf16(p[6], p[7]);
            *(uint2*)(pwB + 2 * kg)     = wlo;
            *(uint2*)(pwB + 8 + 2 * kg) = whi;
            const short8 pa = *(const short8*)(pwB + 4 * kg);
            const short8 bv0 = *(const short8*)(Vt + l16 * VSTR + offB + 32 * t + k0);
            const short8 bv1 = *(const short8*)(Vt + (16 + l16) * VSTR + offB + 32 * t + k0);
            o0B = __builtin_amdgcn_mfma_f32_16x16x32_bf16(pa, bv0, o0B, 0, 0, 0);
            o1B = __builtin_amdgcn_mfma_f32_16x16x32_bf16(pa, bv1, o1B, 0, 0, 0);
        }
    }

    // ---- epilogue: reduce row-sums, normalize, write (both chunks) ----
    srowA += __shfl_xor(srowA, 16);
    srowA += __shfl_xor(srowA, 32);
    srowB += __shfl_xor(srowB, 16);
    srowB += __shfl_xor(srowB, 32);
    #pragma unroll
    for (int r = 0; r < 4; ++r) {
        const float sqA = __shfl(srowA, 4 * kg + r);
        const float invA = 1.0f / sqA;
        float* dstA = out + (size_t)(b * SEQ + q0A + 16 * w + 4 * kg + r) * EMB + h * DH;
        dstA[l16]      = o0A[r] * invA;
        dstA[16 + l16] = o1A[r] * invA;
        const float sqB = __shfl(srowB, 4 * kg + r);
        const float invB = 1.0f / sqB;
        float* dstB = out + (size_t)(b * SEQ + q0B + 16 * w + 4 * kg + r) * EMB + h * DH;
        dstB[l16]      = o0B[r] * invB;
        dstB[16 + l16] = o1B[r] * invB;
    }
}

extern "C" void kernel_launch(void* const* d_in, const int* in_sizes, int n_in,
                              void* d_out, int out_size, void* d_ws, size_t ws_size,
                              hipStream_t stream) {
    const float* q = (const float*)d_in[0];
    const float* k = (const float*)d_in[1];
    const float* v = (const float*)d_in[2];
    float* out = (float*)d_out;
    const int grid = NB * NH * (SEQ / 128);   // 1024 blocks (2 chunks each)
    attn_chunk_kernel<<<grid, 256, 0, stream>>>(q, k, v, out);
}